// Round 5
// baseline (20349.379 us; speedup 1.0000x reference)
//
#include <hip/hip_runtime.h>
#include <hip/hip_bf16.h>
#include <cmath>
#include <cstddef>

// Problem constants (from reference)
#define NN 100000
#define HH 128
#define EE 1600000
#define NH (NN * HH)
#define ALPHA_C 0.1f
#define THETA_C 0.5f
#define EPS_C 1e-5f

constexpr int TR = 64;    // rows per GEMM block
constexpr int AST = 68;   // LDS A^T stride (floats): 16B-aligned rows, b128-clean
constexpr int SCAN_B = 256;
constexpr int NBLK = (NN + SCAN_B - 1) / SCAN_B;   // 391 scan blocks

// ---------------------------------------------------------------------------
__global__ __launch_bounds__(256) void zero_int_k(int* __restrict__ p, int n) {
    int i = blockIdx.x * 256 + threadIdx.x;
    if (i < n) p[i] = 0;
}
__global__ __launch_bounds__(256) void zero_f4_k(float4* __restrict__ p, int n4) {
    int i = blockIdx.x * 256 + threadIdx.x;
    if (i < n4) p[i] = float4{0.f, 0.f, 0.f, 0.f};
}

// ---------------------------------------------------------------------------
// Index dtype detection: int64 (values < 2^31) -> every odd 32-bit word is 0.
__global__ void detect_idx64(const int* __restrict__ p, int* __restrict__ flag) {
    int any = 0;
    for (int i = 0; i < 64; ++i) any |= p[2 * i + 1];
    *flag = (any == 0) ? 1 : 0;
}

__device__ __forceinline__ int load_idx(const void* p, int e, int is64) {
    return is64 ? (int)((const long long*)p)[e] : ((const int*)p)[e];
}

// ---------------------------------------------------------------------------
// CSR build: histogram of dst
__global__ __launch_bounds__(256) void hist_k(
    const void* __restrict__ dstp, const int* __restrict__ flag,
    int* __restrict__ hist)
{
    int e = blockIdx.x * 256 + threadIdx.x;
    if (e >= EE) return;
    atomicAdd(&hist[load_idx(dstp, e, *flag)], 1);
}

__global__ __launch_bounds__(SCAN_B) void scan1_k(
    const int* __restrict__ hist, int* __restrict__ incl, int* __restrict__ bsum)
{
    __shared__ int sh[SCAN_B];
    int t = threadIdx.x;
    int i = blockIdx.x * SCAN_B + t;
    int v = (i < NN) ? hist[i] : 0;
    sh[t] = v;
    __syncthreads();
    for (int off = 1; off < SCAN_B; off <<= 1) {
        int x = (t >= off) ? sh[t - off] : 0;
        __syncthreads();
        sh[t] += x;
        __syncthreads();
    }
    if (i < NN) incl[i] = sh[t];
    if (t == SCAN_B - 1) bsum[blockIdx.x] = sh[t];
}

__global__ __launch_bounds__(512) void scan2_k(int* __restrict__ bsum) {
    __shared__ int sh[512];
    int t = threadIdx.x;
    sh[t] = (t < NBLK) ? bsum[t] : 0;
    __syncthreads();
    for (int off = 1; off < 512; off <<= 1) {
        int x = (t >= off) ? sh[t - off] : 0;
        __syncthreads();
        sh[t] += x;
        __syncthreads();
    }
    if (t < NBLK) bsum[t] = sh[t];
}

__global__ __launch_bounds__(SCAN_B) void scan3_k(
    const int* __restrict__ hist, const int* __restrict__ incl,
    const int* __restrict__ bsum, int* __restrict__ row_ptr,
    int* __restrict__ cursor)
{
    int b = blockIdx.x;
    int i = b * SCAN_B + threadIdx.x;
    if (i < NN) {
        int ex = incl[i] - hist[i] + (b > 0 ? bsum[b - 1] : 0);
        row_ptr[i] = ex;
        cursor[i] = ex;
    }
    if (i == 0) row_ptr[NN] = EE;
}

__global__ __launch_bounds__(256) void fill_k(
    const void* __restrict__ srcp, const void* __restrict__ dstp,
    const int* __restrict__ flag, int* __restrict__ cursor,
    int* __restrict__ sorted_src)
{
    int e = blockIdx.x * 256 + threadIdx.x;
    if (e >= EE) return;
    int is64 = *flag;
    int d = load_idx(dstp, e, is64);
    int pos = atomicAdd(&cursor[d], 1);
    sorted_src[pos] = load_idx(srcp, e, is64);
}

// ---------------------------------------------------------------------------
// CSR gather, 2 edges per iteration (float4/lane; lanes 0-31 edge A, 32-63
// edge B). Optional fused BN+ReLU with scale/shift derived in-register from
// raw channel sum/sumsq stats (computed by the producing GEMM's epilogue).
__global__ __launch_bounds__(256) void gather_k(
    const float* __restrict__ z, const int* __restrict__ row_ptr,
    const int* __restrict__ sorted_src,
    const float* __restrict__ stats,    // [256]: sum, sumsq; null = no BN
    const float* __restrict__ gamma, const float* __restrict__ beta,
    float* __restrict__ msg)
{
    int node = blockIdx.x * 4 + (threadIdx.x >> 6);
    if (node >= NN) return;
    int lane = threadIdx.x & 63;
    int half = lane >> 5;        // which edge of the pair
    int c4 = lane & 31;          // float4 column index

    const bool bn = (stats != nullptr);
    float4 sc = {1.f, 1.f, 1.f, 1.f}, sh = {0.f, 0.f, 0.f, 0.f};
    if (bn) {
        const float invN = 1.f / (float)NN;
        float4 s  = ((const float4*)stats)[c4];
        float4 s2 = ((const float4*)(stats + 128))[c4];
        float4 g  = ((const float4*)gamma)[c4];
        float4 b  = ((const float4*)beta)[c4];
        float m, var;
        m = s.x * invN; var = s2.x * invN - m * m;
        sc.x = rsqrtf(var + EPS_C) * g.x; sh.x = b.x - m * sc.x;
        m = s.y * invN; var = s2.y * invN - m * m;
        sc.y = rsqrtf(var + EPS_C) * g.y; sh.y = b.y - m * sc.y;
        m = s.z * invN; var = s2.z * invN - m * m;
        sc.z = rsqrtf(var + EPS_C) * g.z; sh.z = b.z - m * sc.z;
        m = s.w * invN; var = s2.w * invN - m * m;
        sc.w = rsqrtf(var + EPS_C) * g.w; sh.w = b.w - m * sc.w;
    }

    int e0 = row_ptr[node], e1 = row_ptr[node + 1];
    float4 acc = {0.f, 0.f, 0.f, 0.f};
    for (int e = e0 + half; e < e1; e += 2) {
        int s = sorted_src[e];
        float4 v = ((const float4*)(z + (size_t)s * HH))[c4];
        if (bn) {
            v.x = fmaxf(0.f, v.x * sc.x + sh.x);
            v.y = fmaxf(0.f, v.y * sc.y + sh.y);
            v.z = fmaxf(0.f, v.z * sc.z + sh.z);
            v.w = fmaxf(0.f, v.w * sc.w + sh.w);
        }
        acc.x += v.x; acc.y += v.y; acc.z += v.z; acc.w += v.w;
    }
    // combine the two halves (lane i += lane i+32)
    acc.x += __shfl_down(acc.x, 32);
    acc.y += __shfl_down(acc.y, 32);
    acc.z += __shfl_down(acc.z, 32);
    acc.w += __shfl_down(acc.w, 32);
    if (half == 0)
        ((float4*)(msg + (size_t)node * HH))[c4] = acc;
}

// ---------------------------------------------------------------------------
// Weight prep: Wp[i] = W_in (i==0) else (1-bl_i)*I + bl_i*conv_W[i-1]
__global__ __launch_bounds__(256) void prep_w(
    const float* __restrict__ W_in, const float* __restrict__ conv_W,
    float* __restrict__ Wp)
{
    int i = blockIdx.y;                          // 0..5
    int idx = blockIdx.x * 256 + threadIdx.x;    // 0..16383
    float v;
    if (i == 0) {
        v = W_in[idx];
    } else {
        float bl = logf(THETA_C / (float)i + 1.f);
        int k = idx >> 7, c = idx & 127;
        v = bl * conv_W[(size_t)(i - 1) * 16384 + idx] + ((k == c) ? (1.f - bl) : 0.f);
    }
    Wp[(size_t)i * 16384 + idx] = v;
}

// ---------------------------------------------------------------------------
// 128-col GEMM, residual pre-folded into Wp. Software-pipelined W prefetch
// (8-deep register double buffer). Optional fused BN-stats epilogue: channel
// sum/sumsq reduced in the (dead) As LDS, one atomicAdd pair per channel.
__global__ __launch_bounds__(256, 4) void gemm128(
    const float* __restrict__ src0, const float* __restrict__ src1,
    float cA, float cB, const float* __restrict__ Wp,
    const float* __restrict__ bias, float* __restrict__ out,
    float* __restrict__ statsp, int nrows)
{
    __shared__ float As[HH * AST];   // A^T [k][r]
    const int t = threadIdx.x;
    const int tx = t & 31;           // output cols 4*tx..4*tx+3
    const int ty = t >> 5;           // rows 8*ty..8*ty+7
    const int lane = t & 63, w = t >> 6;
    const int row0 = blockIdx.x * TR;
    const bool useB = (cB != 0.f);

#pragma unroll
    for (int i = 0; i < 8; ++i) {
        int r = (i & 3) * 16 + (lane & 15);
        int k4 = ((i >> 2) * 4 + w) * 4 + (lane >> 4);
        float4 v = {0.f, 0.f, 0.f, 0.f};
        if (row0 + r < nrows) {
            float4 a = ((const float4*)(src0 + (size_t)(row0 + r) * HH))[k4];
            if (useB) {
                float4 b = ((const float4*)(src1 + (size_t)(row0 + r) * HH))[k4];
                v.x = cA * a.x + cB * b.x; v.y = cA * a.y + cB * b.y;
                v.z = cA * a.z + cB * b.z; v.w = cA * a.w + cB * b.w;
            } else {
                v.x = cA * a.x; v.y = cA * a.y; v.z = cA * a.z; v.w = cA * a.w;
            }
        }
        int k = k4 * 4;
        As[(k + 0) * AST + r] = v.x;
        As[(k + 1) * AST + r] = v.y;
        As[(k + 2) * AST + r] = v.z;
        As[(k + 3) * AST + r] = v.w;
    }
    __syncthreads();

    float acc[8][4];
#pragma unroll
    for (int ii = 0; ii < 8; ++ii)
#pragma unroll
        for (int j = 0; j < 4; ++j) acc[ii][j] = 0.f;

    const float4* W4 = (const float4*)Wp;   // row k -> W4[k*32 + tx]
    float4 wbuf[8];
#pragma unroll
    for (int kk = 0; kk < 8; ++kk) wbuf[kk] = W4[kk * 32 + tx];

    for (int k0 = 0; k0 < HH; k0 += 8) {
        float4 wn[8];
        const bool more = (k0 + 8 < HH);
#pragma unroll
        for (int kk = 0; kk < 8; ++kk) {
            if (more) wn[kk] = W4[(k0 + 8 + kk) * 32 + tx];  // prefetch next chunk
            int k = k0 + kk;
            const float* ap = &As[k * AST + ty * 8];
            float4 a0 = *(const float4*)ap;
            float4 a1 = *(const float4*)(ap + 4);
            float a[8] = {a0.x, a0.y, a0.z, a0.w, a1.x, a1.y, a1.z, a1.w};
#pragma unroll
            for (int ii = 0; ii < 8; ++ii) {
                acc[ii][0] += a[ii] * wbuf[kk].x;
                acc[ii][1] += a[ii] * wbuf[kk].y;
                acc[ii][2] += a[ii] * wbuf[kk].z;
                acc[ii][3] += a[ii] * wbuf[kk].w;
            }
        }
        if (more) {
#pragma unroll
            for (int kk = 0; kk < 8; ++kk) wbuf[kk] = wn[kk];
        }
    }

    float4 b4 = {0.f, 0.f, 0.f, 0.f};
    if (bias) b4 = ((const float4*)bias)[tx];
    float cs[4] = {0.f, 0.f, 0.f, 0.f}, cq[4] = {0.f, 0.f, 0.f, 0.f};
    const bool doStats = (statsp != nullptr);
#pragma unroll
    for (int ii = 0; ii < 8; ++ii) {
        int r = row0 + ty * 8 + ii;
        if (r < nrows) {
            float4 v = {acc[ii][0] + b4.x, acc[ii][1] + b4.y,
                        acc[ii][2] + b4.z, acc[ii][3] + b4.w};
            ((float4*)out)[(size_t)r * 32 + tx] = v;
            if (doStats) {
                cs[0] += v.x; cq[0] += v.x * v.x;
                cs[1] += v.y; cq[1] += v.y * v.y;
                cs[2] += v.z; cq[2] += v.z * v.z;
                cs[3] += v.w; cq[3] += v.w * v.w;
            }
        }
    }
    if (doStats) {
        __syncthreads();              // all waves done with As -> reuse as scratch
        float* red = As;              // [0..1023]=sum, [1024..2047]=sumsq
#pragma unroll
        for (int j = 0; j < 4; ++j) {
            red[ty * 128 + tx * 4 + j] = cs[j];
            red[1024 + ty * 128 + tx * 4 + j] = cq[j];
        }
        __syncthreads();
        if (t < 128) {
            float s = 0.f, q = 0.f;
#pragma unroll
            for (int g = 0; g < 8; ++g) {
                s += red[g * 128 + t];
                q += red[1024 + g * 128 + t];
            }
            atomicAdd(&statsp[t], s);
            atomicAdd(&statsp[128 + t], q);
        }
    }
}

// ---------------------------------------------------------------------------
// JumpingKnowledge GEMM: out = concat(z0..z3)[N,512] @ Wjk[512,128] + bjk
// Same pipelined structure per source. out may alias z0.
__global__ __launch_bounds__(256, 4) void gemm_jk(
    const float* __restrict__ z0, const float* __restrict__ z1,
    const float* __restrict__ z2, const float* __restrict__ z3,
    const float* __restrict__ Wjk, const float* __restrict__ bjk,
    float* __restrict__ out, int nrows)
{
    __shared__ float As[HH * AST];
    const int t = threadIdx.x;
    const int tx = t & 31;
    const int ty = t >> 5;
    const int lane = t & 63, w = t >> 6;
    const int row0 = blockIdx.x * TR;

    float acc[8][4];
#pragma unroll
    for (int ii = 0; ii < 8; ++ii)
#pragma unroll
        for (int j = 0; j < 4; ++j) acc[ii][j] = 0.f;

    const float* srcs[4] = {z0, z1, z2, z3};
    for (int j = 0; j < 4; ++j) {
        if (j) __syncthreads();
        const float* Z = srcs[j];
#pragma unroll
        for (int i = 0; i < 8; ++i) {
            int r = (i & 3) * 16 + (lane & 15);
            int k4 = ((i >> 2) * 4 + w) * 4 + (lane >> 4);
            float4 v = {0.f, 0.f, 0.f, 0.f};
            if (row0 + r < nrows)
                v = ((const float4*)(Z + (size_t)(row0 + r) * HH))[k4];
            int k = k4 * 4;
            As[(k + 0) * AST + r] = v.x;
            As[(k + 1) * AST + r] = v.y;
            As[(k + 2) * AST + r] = v.z;
            As[(k + 3) * AST + r] = v.w;
        }
        __syncthreads();

        const float4* W4 = (const float4*)(Wjk + (size_t)j * 128 * HH);
        float4 wbuf[8];
#pragma unroll
        for (int kk = 0; kk < 8; ++kk) wbuf[kk] = W4[kk * 32 + tx];

        for (int k0 = 0; k0 < HH; k0 += 8) {
            float4 wn[8];
            const bool more = (k0 + 8 < HH);
#pragma unroll
            for (int kk = 0; kk < 8; ++kk) {
                if (more) wn[kk] = W4[(k0 + 8 + kk) * 32 + tx];
                int k = k0 + kk;
                const float* ap = &As[k * AST + ty * 8];
                float4 a0 = *(const float4*)ap;
                float4 a1 = *(const float4*)(ap + 4);
                float a[8] = {a0.x, a0.y, a0.z, a0.w, a1.x, a1.y, a1.z, a1.w};
#pragma unroll
                for (int ii = 0; ii < 8; ++ii) {
                    acc[ii][0] += a[ii] * wbuf[kk].x;
                    acc[ii][1] += a[ii] * wbuf[kk].y;
                    acc[ii][2] += a[ii] * wbuf[kk].z;
                    acc[ii][3] += a[ii] * wbuf[kk].w;
                }
            }
            if (more) {
#pragma unroll
                for (int kk = 0; kk < 8; ++kk) wbuf[kk] = wn[kk];
            }
        }
    }

    float4 b4 = ((const float4*)bjk)[tx];
#pragma unroll
    for (int ii = 0; ii < 8; ++ii) {
        int r = row0 + ty * 8 + ii;
        if (r < nrows) {
            float4 v = {acc[ii][0] + b4.x, acc[ii][1] + b4.y,
                        acc[ii][2] + b4.z, acc[ii][3] + b4.w};
            ((float4*)out)[(size_t)r * 32 + tx] = v;
        }
    }
}

// ---------------------------------------------------------------------------
extern "C" void kernel_launch(void* const* d_in, const int* in_sizes, int n_in,
                              void* d_out, int out_size, void* d_ws, size_t ws_size,
                              hipStream_t stream)
{
    const float* x       = (const float*)d_in[0];
    const float* W_in    = (const float*)d_in[1];
    const float* b_in    = (const float*)d_in[2];
    const float* conv_W  = (const float*)d_in[3];
    const float* bn_g    = (const float*)d_in[4];
    const float* bn_b    = (const float*)d_in[5];
    const float* W_jk    = (const float*)d_in[6];
    const float* b_jk    = (const float*)d_in[7];
    const void*  srcp    = d_in[8];
    const void*  dstp    = d_in[9];

    // Workspace: 5*NH floats (244 MiB) + stats3 + CSR (~7.3 MB) + Wp (384 KB)
    float* ws     = (float*)d_ws;
    float* x0     = ws;                        // [N,H] z0, residual
    float* msg    = ws + (size_t)NH;           // [N,H] gather target
    float* zs0    = ws + 2 * (size_t)NH;       // z per layer; zs0 reused as JK out
    float* zs1    = ws + 3 * (size_t)NH;
    float* zs2    = ws + 4 * (size_t)NH;
    float* stats3 = ws + 5 * (size_t)NH;       // [3][256] sum/sumsq per BN layer
    int*   flag       = (int*)(stats3 + 768);
    int*   hist       = flag + 1;              // [NN]
    int*   incl       = hist + NN;             // [NN]
    int*   row_ptr    = incl + NN;             // [NN+1]
    int*   cursor     = row_ptr + NN + 1;      // [NN]
    int*   bsum       = cursor + NN;           // [NBLK]
    int*   sorted_src = bsum + NBLK + 1;       // [EE]
    float* Wp         = (float*)(sorted_src + EE);  // [6][128][128]

    const int GEMM_GRID = (NN + TR - 1) / TR;     // 1563
    const int EDGE_GRID = (EE + 255) / 256;       // 6250
    const int NODE_GRID = (NN + 3) / 4;           // 25000

    // ---- CSR build + weight prep + stats zero (once per launch) ----
    detect_idx64<<<1, 1, 0, stream>>>((const int*)srcp, flag);
    zero_int_k<<<(NN + 255) / 256, 256, 0, stream>>>(hist, NN);
    zero_f4_k<<<1, 192, 0, stream>>>((float4*)stats3, 192);
    hist_k<<<EDGE_GRID, 256, 0, stream>>>(dstp, flag, hist);
    scan1_k<<<NBLK, SCAN_B, 0, stream>>>(hist, incl, bsum);
    scan2_k<<<1, 512, 0, stream>>>(bsum);
    scan3_k<<<NBLK, SCAN_B, 0, stream>>>(hist, incl, bsum, row_ptr, cursor);
    fill_k<<<EDGE_GRID, 256, 0, stream>>>(srcp, dstp, flag, cursor, sorted_src);
    prep_w<<<dim3(64, 6), 256, 0, stream>>>(W_in, conv_W, Wp);

    // ---- x0 = x @ W_in + b_in ----
    gemm128<<<GEMM_GRID, 256, 0, stream>>>(x, x, 1.f, 0.f, Wp, b_in, x0,
                                           nullptr, NN);

    const float* act = x0;
    const float* stats_cur = nullptr;   // BN stats for act (null = no BN)
    const float* g_cur = nullptr;
    const float* b_cur = nullptr;

    for (int i = 0; i < 5; ++i) {
        gather_k<<<NODE_GRID, 256, 0, stream>>>(act, row_ptr, sorted_src,
                                                stats_cur, g_cur, b_cur, msg);

        float* zraw = (i >= 3) ? (float*)d_out : (zs0 + (size_t)i * NH);
        float* stats_next = (i < 3) ? (stats3 + (size_t)i * 256) : nullptr;
        gemm128<<<GEMM_GRID, 256, 0, stream>>>(msg, x0, 1.f - ALPHA_C, ALPHA_C,
                                               Wp + (size_t)(i + 1) * 16384,
                                               nullptr, zraw, stats_next, NN);
        if (i < 3) {
            act = zraw;                 // BN+ReLU fused into next gather
            stats_cur = stats_next;
            g_cur = bn_g + (size_t)i * HH;
            b_cur = bn_b + (size_t)i * HH;
        } else if (i == 3) {
            gemm_jk<<<GEMM_GRID, 256, 0, stream>>>(zs0, zs1, zs2,
                                                   (const float*)d_out, W_jk, b_jk,
                                                   zs0, NN);
            act = zs0;
            stats_cur = nullptr;
            g_cur = nullptr;
            b_cur = nullptr;
        }
    }
}

// Round 6
// 1592.572 us; speedup vs baseline: 12.7777x; 12.7777x over previous
//
#include <hip/hip_runtime.h>
#include <hip/hip_bf16.h>
#include <cmath>
#include <cstddef>

// Problem constants (from reference)
#define NN 100000
#define HH 128
#define EE 1600000
#define NH (NN * HH)
#define ALPHA_C 0.1f
#define THETA_C 0.5f
#define EPS_C 1e-5f

constexpr int TR = 64;    // rows per GEMM block
constexpr int AST = 68;   // LDS A^T stride (floats): 16B-aligned rows, b128-clean
constexpr int SCAN_B = 256;
constexpr int NBLK = (NN + SCAN_B - 1) / SCAN_B;   // 391 scan blocks

// ---------------------------------------------------------------------------
__global__ __launch_bounds__(256) void zero_int_k(int* __restrict__ p, int n) {
    int i = blockIdx.x * 256 + threadIdx.x;
    if (i < n) p[i] = 0;
}
__global__ __launch_bounds__(256) void zero_f4_k(float4* __restrict__ p, int n4) {
    int i = blockIdx.x * 256 + threadIdx.x;
    if (i < n4) p[i] = float4{0.f, 0.f, 0.f, 0.f};
}

// ---------------------------------------------------------------------------
// Index dtype detection: int64 (values < 2^31) -> every odd 32-bit word is 0.
__global__ void detect_idx64(const int* __restrict__ p, int* __restrict__ flag) {
    int any = 0;
    for (int i = 0; i < 64; ++i) any |= p[2 * i + 1];
    *flag = (any == 0) ? 1 : 0;
}

__device__ __forceinline__ int load_idx(const void* p, int e, int is64) {
    return is64 ? (int)((const long long*)p)[e] : ((const int*)p)[e];
}

// ---------------------------------------------------------------------------
// CSR build: histogram of dst
__global__ __launch_bounds__(256) void hist_k(
    const void* __restrict__ dstp, const int* __restrict__ flag,
    int* __restrict__ hist)
{
    int e = blockIdx.x * 256 + threadIdx.x;
    if (e >= EE) return;
    atomicAdd(&hist[load_idx(dstp, e, *flag)], 1);
}

__global__ __launch_bounds__(SCAN_B) void scan1_k(
    const int* __restrict__ hist, int* __restrict__ incl, int* __restrict__ bsum)
{
    __shared__ int sh[SCAN_B];
    int t = threadIdx.x;
    int i = blockIdx.x * SCAN_B + t;
    int v = (i < NN) ? hist[i] : 0;
    sh[t] = v;
    __syncthreads();
    for (int off = 1; off < SCAN_B; off <<= 1) {
        int x = (t >= off) ? sh[t - off] : 0;
        __syncthreads();
        sh[t] += x;
        __syncthreads();
    }
    if (i < NN) incl[i] = sh[t];
    if (t == SCAN_B - 1) bsum[blockIdx.x] = sh[t];
}

__global__ __launch_bounds__(512) void scan2_k(int* __restrict__ bsum) {
    __shared__ int sh[512];
    int t = threadIdx.x;
    sh[t] = (t < NBLK) ? bsum[t] : 0;
    __syncthreads();
    for (int off = 1; off < 512; off <<= 1) {
        int x = (t >= off) ? sh[t - off] : 0;
        __syncthreads();
        sh[t] += x;
        __syncthreads();
    }
    if (t < NBLK) bsum[t] = sh[t];
}

__global__ __launch_bounds__(SCAN_B) void scan3_k(
    const int* __restrict__ hist, const int* __restrict__ incl,
    const int* __restrict__ bsum, int* __restrict__ row_ptr,
    int* __restrict__ cursor)
{
    int b = blockIdx.x;
    int i = b * SCAN_B + threadIdx.x;
    if (i < NN) {
        int ex = incl[i] - hist[i] + (b > 0 ? bsum[b - 1] : 0);
        row_ptr[i] = ex;
        cursor[i] = ex;
    }
    if (i == 0) row_ptr[NN] = EE;
}

__global__ __launch_bounds__(256) void fill_k(
    const void* __restrict__ srcp, const void* __restrict__ dstp,
    const int* __restrict__ flag, int* __restrict__ cursor,
    int* __restrict__ sorted_src)
{
    int e = blockIdx.x * 256 + threadIdx.x;
    if (e >= EE) return;
    int is64 = *flag;
    int d = load_idx(dstp, e, is64);
    int pos = atomicAdd(&cursor[d], 1);
    sorted_src[pos] = load_idx(srcp, e, is64);
}

// ---------------------------------------------------------------------------
// CSR gather, 2 edges per iteration (float4/lane; lanes 0-31 edge A, 32-63
// edge B). Optional fused BN+ReLU with scale/shift derived in-register from
// raw channel sum/sumsq stats (computed by the producing GEMM's epilogue).
__global__ __launch_bounds__(256) void gather_k(
    const float* __restrict__ z, const int* __restrict__ row_ptr,
    const int* __restrict__ sorted_src,
    const float* __restrict__ stats,    // [256]: sum, sumsq; null = no BN
    const float* __restrict__ gamma, const float* __restrict__ beta,
    float* __restrict__ msg)
{
    int node = blockIdx.x * 4 + (threadIdx.x >> 6);
    if (node >= NN) return;
    int lane = threadIdx.x & 63;
    int half = lane >> 5;        // which edge of the pair
    int c4 = lane & 31;          // float4 column index

    const bool bn = (stats != nullptr);
    float4 sc = {1.f, 1.f, 1.f, 1.f}, sh = {0.f, 0.f, 0.f, 0.f};
    if (bn) {
        const float invN = 1.f / (float)NN;
        float4 s  = ((const float4*)stats)[c4];
        float4 s2 = ((const float4*)(stats + 128))[c4];
        float4 g  = ((const float4*)gamma)[c4];
        float4 b  = ((const float4*)beta)[c4];
        float m, var;
        m = s.x * invN; var = s2.x * invN - m * m;
        sc.x = rsqrtf(var + EPS_C) * g.x; sh.x = b.x - m * sc.x;
        m = s.y * invN; var = s2.y * invN - m * m;
        sc.y = rsqrtf(var + EPS_C) * g.y; sh.y = b.y - m * sc.y;
        m = s.z * invN; var = s2.z * invN - m * m;
        sc.z = rsqrtf(var + EPS_C) * g.z; sh.z = b.z - m * sc.z;
        m = s.w * invN; var = s2.w * invN - m * m;
        sc.w = rsqrtf(var + EPS_C) * g.w; sh.w = b.w - m * sc.w;
    }

    int e0 = row_ptr[node], e1 = row_ptr[node + 1];
    float4 acc = {0.f, 0.f, 0.f, 0.f};
    for (int e = e0 + half; e < e1; e += 2) {
        int s = sorted_src[e];
        float4 v = ((const float4*)(z + (size_t)s * HH))[c4];
        if (bn) {
            v.x = fmaxf(0.f, v.x * sc.x + sh.x);
            v.y = fmaxf(0.f, v.y * sc.y + sh.y);
            v.z = fmaxf(0.f, v.z * sc.z + sh.z);
            v.w = fmaxf(0.f, v.w * sc.w + sh.w);
        }
        acc.x += v.x; acc.y += v.y; acc.z += v.z; acc.w += v.w;
    }
    // combine the two halves (lane i += lane i+32)
    acc.x += __shfl_down(acc.x, 32);
    acc.y += __shfl_down(acc.y, 32);
    acc.z += __shfl_down(acc.z, 32);
    acc.w += __shfl_down(acc.w, 32);
    if (half == 0)
        ((float4*)(msg + (size_t)node * HH))[c4] = acc;
}

// ---------------------------------------------------------------------------
// Weight prep: Wp[i] = W_in (i==0) else (1-bl_i)*I + bl_i*conv_W[i-1]
__global__ __launch_bounds__(256) void prep_w(
    const float* __restrict__ W_in, const float* __restrict__ conv_W,
    float* __restrict__ Wp)
{
    int i = blockIdx.y;                          // 0..5
    int idx = blockIdx.x * 256 + threadIdx.x;    // 0..16383
    float v;
    if (i == 0) {
        v = W_in[idx];
    } else {
        float bl = logf(THETA_C / (float)i + 1.f);
        int k = idx >> 7, c = idx & 127;
        v = bl * conv_W[(size_t)(i - 1) * 16384 + idx] + ((k == c) ? (1.f - bl) : 0.f);
    }
    Wp[(size_t)i * 16384 + idx] = v;
}

// ---------------------------------------------------------------------------
// 128-col GEMM, residual pre-folded into Wp. 4-deep register double-buffer
// for W (fits the 128-VGPR cap of __launch_bounds__(256,4) WITHOUT spilling;
// 8-deep spilled to scratch: R5, 5.9 GB FETCH/dispatch, VALUBusy 0.9%).
// Optional fused BN-stats epilogue reduced through the dead As LDS.
__global__ __launch_bounds__(256, 4) void gemm128(
    const float* __restrict__ src0, const float* __restrict__ src1,
    float cA, float cB, const float* __restrict__ Wp,
    const float* __restrict__ bias, float* __restrict__ out,
    float* __restrict__ statsp, int nrows)
{
    __shared__ float As[HH * AST];   // A^T [k][r]
    const int t = threadIdx.x;
    const int tx = t & 31;           // output cols 4*tx..4*tx+3
    const int ty = t >> 5;           // rows 8*ty..8*ty+7
    const int lane = t & 63, w = t >> 6;
    const int row0 = blockIdx.x * TR;
    const bool useB = (cB != 0.f);

#pragma unroll
    for (int i = 0; i < 8; ++i) {
        int r = (i & 3) * 16 + (lane & 15);
        int k4 = ((i >> 2) * 4 + w) * 4 + (lane >> 4);
        float4 v = {0.f, 0.f, 0.f, 0.f};
        if (row0 + r < nrows) {
            float4 a = ((const float4*)(src0 + (size_t)(row0 + r) * HH))[k4];
            if (useB) {
                float4 b = ((const float4*)(src1 + (size_t)(row0 + r) * HH))[k4];
                v.x = cA * a.x + cB * b.x; v.y = cA * a.y + cB * b.y;
                v.z = cA * a.z + cB * b.z; v.w = cA * a.w + cB * b.w;
            } else {
                v.x = cA * a.x; v.y = cA * a.y; v.z = cA * a.z; v.w = cA * a.w;
            }
        }
        int k = k4 * 4;
        As[(k + 0) * AST + r] = v.x;
        As[(k + 1) * AST + r] = v.y;
        As[(k + 2) * AST + r] = v.z;
        As[(k + 3) * AST + r] = v.w;
    }
    __syncthreads();

    float acc[8][4];
#pragma unroll
    for (int ii = 0; ii < 8; ++ii)
#pragma unroll
        for (int j = 0; j < 4; ++j) acc[ii][j] = 0.f;

    const float4* W4 = (const float4*)Wp;   // row k -> W4[k*32 + tx]
    float4 wbuf[4];
#pragma unroll
    for (int kk = 0; kk < 4; ++kk) wbuf[kk] = W4[kk * 32 + tx];

    for (int k0 = 0; k0 < HH; k0 += 4) {
        float4 wn[4];
        const bool more = (k0 + 4 < HH);
#pragma unroll
        for (int kk = 0; kk < 4; ++kk) {
            if (more) wn[kk] = W4[(k0 + 4 + kk) * 32 + tx];  // prefetch next chunk
            int k = k0 + kk;
            const float* ap = &As[k * AST + ty * 8];
            float4 a0 = *(const float4*)ap;
            float4 a1 = *(const float4*)(ap + 4);
            float a[8] = {a0.x, a0.y, a0.z, a0.w, a1.x, a1.y, a1.z, a1.w};
#pragma unroll
            for (int ii = 0; ii < 8; ++ii) {
                acc[ii][0] += a[ii] * wbuf[kk].x;
                acc[ii][1] += a[ii] * wbuf[kk].y;
                acc[ii][2] += a[ii] * wbuf[kk].z;
                acc[ii][3] += a[ii] * wbuf[kk].w;
            }
        }
        if (more) {
#pragma unroll
            for (int kk = 0; kk < 4; ++kk) wbuf[kk] = wn[kk];
        }
    }

    float4 b4 = {0.f, 0.f, 0.f, 0.f};
    if (bias) b4 = ((const float4*)bias)[tx];
    float cs[4] = {0.f, 0.f, 0.f, 0.f}, cq[4] = {0.f, 0.f, 0.f, 0.f};
    const bool doStats = (statsp != nullptr);
#pragma unroll
    for (int ii = 0; ii < 8; ++ii) {
        int r = row0 + ty * 8 + ii;
        if (r < nrows) {
            float4 v = {acc[ii][0] + b4.x, acc[ii][1] + b4.y,
                        acc[ii][2] + b4.z, acc[ii][3] + b4.w};
            ((float4*)out)[(size_t)r * 32 + tx] = v;
            if (doStats) {
                cs[0] += v.x; cq[0] += v.x * v.x;
                cs[1] += v.y; cq[1] += v.y * v.y;
                cs[2] += v.z; cq[2] += v.z * v.z;
                cs[3] += v.w; cq[3] += v.w * v.w;
            }
        }
    }
    if (doStats) {
        __syncthreads();              // all waves done with As -> reuse as scratch
        float* red = As;              // [0..1023]=sum, [1024..2047]=sumsq
#pragma unroll
        for (int j = 0; j < 4; ++j) {
            red[ty * 128 + tx * 4 + j] = cs[j];
            red[1024 + ty * 128 + tx * 4 + j] = cq[j];
        }
        __syncthreads();
        if (t < 128) {
            float s = 0.f, q = 0.f;
#pragma unroll
            for (int g = 0; g < 8; ++g) {
                s += red[g * 128 + t];
                q += red[1024 + g * 128 + t];
            }
            atomicAdd(&statsp[t], s);
            atomicAdd(&statsp[128 + t], q);
        }
    }
}

// ---------------------------------------------------------------------------
// JumpingKnowledge GEMM: out = concat(z0..z3)[N,512] @ Wjk[512,128] + bjk
// Same 4-deep pipelined structure per source. out may alias z0.
__global__ __launch_bounds__(256, 4) void gemm_jk(
    const float* __restrict__ z0, const float* __restrict__ z1,
    const float* __restrict__ z2, const float* __restrict__ z3,
    const float* __restrict__ Wjk, const float* __restrict__ bjk,
    float* __restrict__ out, int nrows)
{
    __shared__ float As[HH * AST];
    const int t = threadIdx.x;
    const int tx = t & 31;
    const int ty = t >> 5;
    const int lane = t & 63, w = t >> 6;
    const int row0 = blockIdx.x * TR;

    float acc[8][4];
#pragma unroll
    for (int ii = 0; ii < 8; ++ii)
#pragma unroll
        for (int j = 0; j < 4; ++j) acc[ii][j] = 0.f;

    const float* srcs[4] = {z0, z1, z2, z3};
    for (int j = 0; j < 4; ++j) {
        if (j) __syncthreads();
        const float* Z = srcs[j];
#pragma unroll
        for (int i = 0; i < 8; ++i) {
            int r = (i & 3) * 16 + (lane & 15);
            int k4 = ((i >> 2) * 4 + w) * 4 + (lane >> 4);
            float4 v = {0.f, 0.f, 0.f, 0.f};
            if (row0 + r < nrows)
                v = ((const float4*)(Z + (size_t)(row0 + r) * HH))[k4];
            int k = k4 * 4;
            As[(k + 0) * AST + r] = v.x;
            As[(k + 1) * AST + r] = v.y;
            As[(k + 2) * AST + r] = v.z;
            As[(k + 3) * AST + r] = v.w;
        }
        __syncthreads();

        const float4* W4 = (const float4*)(Wjk + (size_t)j * 128 * HH);
        float4 wbuf[4];
#pragma unroll
        for (int kk = 0; kk < 4; ++kk) wbuf[kk] = W4[kk * 32 + tx];

        for (int k0 = 0; k0 < HH; k0 += 4) {
            float4 wn[4];
            const bool more = (k0 + 4 < HH);
#pragma unroll
            for (int kk = 0; kk < 4; ++kk) {
                if (more) wn[kk] = W4[(k0 + 4 + kk) * 32 + tx];
                int k = k0 + kk;
                const float* ap = &As[k * AST + ty * 8];
                float4 a0 = *(const float4*)ap;
                float4 a1 = *(const float4*)(ap + 4);
                float a[8] = {a0.x, a0.y, a0.z, a0.w, a1.x, a1.y, a1.z, a1.w};
#pragma unroll
                for (int ii = 0; ii < 8; ++ii) {
                    acc[ii][0] += a[ii] * wbuf[kk].x;
                    acc[ii][1] += a[ii] * wbuf[kk].y;
                    acc[ii][2] += a[ii] * wbuf[kk].z;
                    acc[ii][3] += a[ii] * wbuf[kk].w;
                }
            }
            if (more) {
#pragma unroll
                for (int kk = 0; kk < 4; ++kk) wbuf[kk] = wn[kk];
            }
        }
    }

    float4 b4 = ((const float4*)bjk)[tx];
#pragma unroll
    for (int ii = 0; ii < 8; ++ii) {
        int r = row0 + ty * 8 + ii;
        if (r < nrows) {
            float4 v = {acc[ii][0] + b4.x, acc[ii][1] + b4.y,
                        acc[ii][2] + b4.z, acc[ii][3] + b4.w};
            ((float4*)out)[(size_t)r * 32 + tx] = v;
        }
    }
}

// ---------------------------------------------------------------------------
extern "C" void kernel_launch(void* const* d_in, const int* in_sizes, int n_in,
                              void* d_out, int out_size, void* d_ws, size_t ws_size,
                              hipStream_t stream)
{
    const float* x       = (const float*)d_in[0];
    const float* W_in    = (const float*)d_in[1];
    const float* b_in    = (const float*)d_in[2];
    const float* conv_W  = (const float*)d_in[3];
    const float* bn_g    = (const float*)d_in[4];
    const float* bn_b    = (const float*)d_in[5];
    const float* W_jk    = (const float*)d_in[6];
    const float* b_jk    = (const float*)d_in[7];
    const void*  srcp    = d_in[8];
    const void*  dstp    = d_in[9];

    // Workspace: 5*NH floats (244 MiB) + stats3 + CSR (~7.3 MB) + Wp (384 KB)
    float* ws     = (float*)d_ws;
    float* x0     = ws;                        // [N,H] z0, residual
    float* msg    = ws + (size_t)NH;           // [N,H] gather target
    float* zs0    = ws + 2 * (size_t)NH;       // z per layer; zs0 reused as JK out
    float* zs1    = ws + 3 * (size_t)NH;
    float* zs2    = ws + 4 * (size_t)NH;
    float* stats3 = ws + 5 * (size_t)NH;       // [3][256] sum/sumsq per BN layer
    int*   flag       = (int*)(stats3 + 768);
    int*   hist       = flag + 1;              // [NN]
    int*   incl       = hist + NN;             // [NN]
    int*   row_ptr    = incl + NN;             // [NN+1]
    int*   cursor     = row_ptr + NN + 1;      // [NN]
    int*   bsum       = cursor + NN;           // [NBLK]
    int*   sorted_src = bsum + NBLK + 1;       // [EE]
    float* Wp         = (float*)(sorted_src + EE);  // [6][128][128]

    const int GEMM_GRID = (NN + TR - 1) / TR;     // 1563
    const int EDGE_GRID = (EE + 255) / 256;       // 6250
    const int NODE_GRID = (NN + 3) / 4;           // 25000

    // ---- CSR build + weight prep + stats zero (once per launch) ----
    detect_idx64<<<1, 1, 0, stream>>>((const int*)srcp, flag);
    zero_int_k<<<(NN + 255) / 256, 256, 0, stream>>>(hist, NN);
    zero_f4_k<<<1, 192, 0, stream>>>((float4*)stats3, 192);
    hist_k<<<EDGE_GRID, 256, 0, stream>>>(dstp, flag, hist);
    scan1_k<<<NBLK, SCAN_B, 0, stream>>>(hist, incl, bsum);
    scan2_k<<<1, 512, 0, stream>>>(bsum);
    scan3_k<<<NBLK, SCAN_B, 0, stream>>>(hist, incl, bsum, row_ptr, cursor);
    fill_k<<<EDGE_GRID, 256, 0, stream>>>(srcp, dstp, flag, cursor, sorted_src);
    prep_w<<<dim3(64, 6), 256, 0, stream>>>(W_in, conv_W, Wp);

    // ---- x0 = x @ W_in + b_in ----
    gemm128<<<GEMM_GRID, 256, 0, stream>>>(x, x, 1.f, 0.f, Wp, b_in, x0,
                                           nullptr, NN);

    const float* act = x0;
    const float* stats_cur = nullptr;   // BN stats for act (null = no BN)
    const float* g_cur = nullptr;
    const float* b_cur = nullptr;

    for (int i = 0; i < 5; ++i) {
        gather_k<<<NODE_GRID, 256, 0, stream>>>(act, row_ptr, sorted_src,
                                                stats_cur, g_cur, b_cur, msg);

        float* zraw = (i >= 3) ? (float*)d_out : (zs0 + (size_t)i * NH);
        float* stats_next = (i < 3) ? (stats3 + (size_t)i * 256) : nullptr;
        gemm128<<<GEMM_GRID, 256, 0, stream>>>(msg, x0, 1.f - ALPHA_C, ALPHA_C,
                                               Wp + (size_t)(i + 1) * 16384,
                                               nullptr, zraw, stats_next, NN);
        if (i < 3) {
            act = zraw;                 // BN+ReLU fused into next gather
            stats_cur = stats_next;
            g_cur = bn_g + (size_t)i * HH;
            b_cur = bn_b + (size_t)i * HH;
        } else if (i == 3) {
            gemm_jk<<<GEMM_GRID, 256, 0, stream>>>(zs0, zs1, zs2,
                                                   (const float*)d_out, W_jk, b_jk,
                                                   zs0, NN);
            act = zs0;
            stats_cur = nullptr;
            g_cur = nullptr;
            b_cur = nullptr;
        }
    }
}